// Round 3
// baseline (173.196 us; speedup 1.0000x reference)
//
#include <hip/hip_runtime.h>

#define IN_DIM 2048
#define OUT_DIM 2048
#define EPS 1e-8f

#define BM 128
#define BN 256
#define BK 64
#define NT (IN_DIM / BK)       // 32 K-tiles
#define SLOT 24576             // A 8K + B 16K per slot (granule-major)
#define LDS_SZ 73728           // 3 slots = 72 KiB -> 2 blocks/CU (160 KiB)

using int32x4 = __attribute__((ext_vector_type(4))) int;

// ---------------- Kernel 1: sum of |W| ----------------
__global__ __launch_bounds__(256) void absum_kernel(const float* __restrict__ w,
                                                    double* __restrict__ sum, int n4) {
    int tid = blockIdx.x * blockDim.x + threadIdx.x;
    int stride = gridDim.x * blockDim.x;
    float s = 0.f;
    for (int i = tid; i < n4; i += stride) {
        float4 v = ((const float4*)w)[i];
        s += fabsf(v.x) + fabsf(v.y) + fabsf(v.z) + fabsf(v.w);
    }
    for (int off = 32; off; off >>= 1) s += __shfl_down(s, off);
    __shared__ float wsum[4];
    int lane = threadIdx.x & 63, wave = threadIdx.x >> 6;
    if (lane == 0) wsum[wave] = s;
    __syncthreads();
    if (threadIdx.x == 0) {
        double t = (double)wsum[0] + (double)wsum[1] + (double)wsum[2] + (double)wsum[3];
        atomicAdd(sum, t);
    }
}

// ---------------- Kernel 2: quantize W to ternary int8 ----------------
__global__ __launch_bounds__(256) void quantw_kernel(const float* __restrict__ w,
                                                     const double* __restrict__ sumptr,
                                                     signed char* __restrict__ wq,
                                                     float* __restrict__ alpha_out, int n4) {
    float alpha = fmaxf((float)(*sumptr * (1.0 / (double)(IN_DIM * OUT_DIM))), EPS);
    int i = blockIdx.x * blockDim.x + threadIdx.x;
    if (i == 0) *alpha_out = alpha;
    if (i >= n4) return;
    float4 v = ((const float4*)w)[i];
    char4 q;
    q.x = (signed char)fminf(fmaxf(rintf(v.x / alpha), -1.f), 1.f);
    q.y = (signed char)fminf(fmaxf(rintf(v.y / alpha), -1.f), 1.f);
    q.z = (signed char)fminf(fmaxf(rintf(v.z / alpha), -1.f), 1.f);
    q.w = (signed char)fminf(fmaxf(rintf(v.w / alpha), -1.f), 1.f);
    ((char4*)wq)[i] = q;
}

// ---------------- Kernel 3: per-token beta + quantize x ----------------
__global__ __launch_bounds__(256) void quantx_kernel(const float* __restrict__ x,
                                                     signed char* __restrict__ xq,
                                                     float* __restrict__ beta_arr,
                                                     int tokens) {
    const int tid = threadIdx.x;
    const int lane = tid & 63, wave = tid >> 6;
    __shared__ float wmax[4];
    for (int t = blockIdx.x; t < tokens; t += gridDim.x) {
        const float4* row = (const float4*)(x + (size_t)t * IN_DIM);
        float4 v0 = row[tid];
        float4 v1 = row[tid + 256];
        float m = fmaxf(fmaxf(fmaxf(fabsf(v0.x), fabsf(v0.y)), fmaxf(fabsf(v0.z), fabsf(v0.w))),
                        fmaxf(fmaxf(fabsf(v1.x), fabsf(v1.y)), fmaxf(fabsf(v1.z), fabsf(v1.w))));
        for (int off = 32; off; off >>= 1) m = fmaxf(m, __shfl_xor(m, off));
        if (lane == 0) wmax[wave] = m;
        __syncthreads();
        m = fmaxf(fmaxf(wmax[0], wmax[1]), fmaxf(wmax[2], wmax[3]));
        float beta = fmaxf(m * (1.f / 127.f), EPS);
        if (tid == 0) beta_arr[t] = beta;
        char4 q0, q1;
        q0.x = (signed char)fminf(fmaxf(rintf(v0.x / beta), -127.f), 127.f);
        q0.y = (signed char)fminf(fmaxf(rintf(v0.y / beta), -127.f), 127.f);
        q0.z = (signed char)fminf(fmaxf(rintf(v0.z / beta), -127.f), 127.f);
        q0.w = (signed char)fminf(fmaxf(rintf(v0.w / beta), -127.f), 127.f);
        q1.x = (signed char)fminf(fmaxf(rintf(v1.x / beta), -127.f), 127.f);
        q1.y = (signed char)fminf(fmaxf(rintf(v1.y / beta), -127.f), 127.f);
        q1.z = (signed char)fminf(fmaxf(rintf(v1.z / beta), -127.f), 127.f);
        q1.w = (signed char)fminf(fmaxf(rintf(v1.w / beta), -127.f), 127.f);
        char4* orow = (char4*)(xq + (size_t)t * IN_DIM);
        orow[tid] = q0;
        orow[tid + 256] = q1;
        __syncthreads();
    }
}

// ---------------- GEMM helper ----------------
__device__ __forceinline__ void gll(const signed char* g, signed char* l) {
    __builtin_amdgcn_global_load_lds((const __attribute__((address_space(1))) void*)g,
        (__attribute__((address_space(3))) void*)l, 16, 0, 0);
}

// ---------------- Kernel 4: int8 MFMA GEMM, 128x256 tile, 2 blocks/CU ----------------
// 512 threads = 8 waves (2M x 4N); wave-tile 64x64; acc[4][4] = 64 VGPR;
// __launch_bounds__(512,4) caps total regs at 128/wave -> 4 waves/SIMD ->
// TWO blocks resident per CU (72 KiB LDS each). Two independent barrier groups:
// while one block's waves drain ds_reads / sit at a barrier, the other block's
// waves occupy the MFMA pipe. This is the TLP the single-block 256-reg config
// could not have (rounds 0/2: 8 waves/CU lockstep -> zero read/MFMA overlap).
// LDS slot (24 KiB): A 128x64 @0 (8 granules), B 256x64 @8192 (16 granules);
// granule-major: addr = g*1024 + kg*256 + r*16 (row=16g+r, k=16*kg) -> conflict-free
// ds_read_b128 and linear wave-uniform gll destinations. 3-slot rotation,
// depth-2 prefetch, counted vmcnt(3) (never 0 in steady state), 1 barrier/K-tile.
// Grid (8,128): XCD = bid%8 = col-block -> each B-panel (512 KiB) pinned to one XCD L2.
__global__ __launch_bounds__(512, 4) void gemm_kernel(const signed char* __restrict__ xq,
                                                      const signed char* __restrict__ wq,
                                                      const float* __restrict__ beta,
                                                      const float* __restrict__ alpha_p,
                                                      float* __restrict__ out) {
    extern __shared__ signed char lds[];   // 73728
    const int tid = threadIdx.x;
    const int lane = tid & 63;
    const int wave = tid >> 6;
    const int wm = wave >> 2;              // 0..1 (row half)
    const int wn = wave & 3;               // 0..3 (col quarter)
    const int col0 = blockIdx.x * BN;
    const int row0 = blockIdx.y * BM;

    // staging: thread t writes LDS bytes [t*16, +16) in each region.
    // A region 8 KiB: 1 chunk/thread; B region 16 KiB: 2 chunks/thread.
    // chunk f=t*16 -> granule g=t>>6, kg=(t>>4)&3, r=t&15 -> src row 16g+r, k=16*kg
    const int f = tid * 16;
    const int srow = ((tid >> 6) << 4) + (tid & 15);     // 0..127
    const int skg = ((tid >> 4) & 3) << 4;
    const signed char* aP  = xq + (size_t)(row0 + srow) * IN_DIM + skg;
    const signed char* b0P = wq + (size_t)(col0 + srow) * IN_DIM + skg;
    const signed char* b1P = wq + (size_t)(col0 + 128 + srow) * IN_DIM + skg;

    // fragment addressing (16x16x64): lane&15 = row-in-16, lane>>4 = 16B k-group
    const int kr = ((lane >> 4) << 8) + ((lane & 15) << 4);
    const int aoff = (wm << 12) + kr;              // + m*1024, m<4
    const int boff = 8192 + (wn << 12) + kr;       // + n*1024, n<4

    int32x4 acc[4][4] = {};

    // prologue: stage tiles 0,1 into slots 0,1 (3 glls each: A, B0, B1)
    gll(aP, lds + f);  gll(b0P, lds + 8192 + f);  gll(b1P, lds + 16384 + f);
    gll(aP + BK, lds + SLOT + f);
    gll(b0P + BK, lds + SLOT + 8192 + f);
    gll(b1P + BK, lds + SLOT + 16384 + f);
    asm volatile("s_waitcnt vmcnt(3)" ::: "memory");   // tile 0's 3 landed
    __builtin_amdgcn_s_barrier();

    int s = 0, d = 2;   // read slot = T%3, stage dest = (T+2)%3
    for (int T = 0; T < NT; ++T) {
        const signed char* ls = lds + s * SLOT;
        signed char* ldst = lds + d * SLOT;
        const size_t ko = (size_t)(T + 2) * BK;
        int32x4 af[4], bf[4];
        // reads ordered so cluster-1 deps (af0,af1,bf0-3) issue first; af2/af3
        // drain under cluster 1 (compiler emits counted lgkmcnt at use sites)
        af[0] = *(const int32x4*)(ls + aoff);
        af[1] = *(const int32x4*)(ls + aoff + 1024);
#pragma unroll
        for (int n = 0; n < 4; ++n) bf[n] = *(const int32x4*)(ls + boff + n * 1024);
        if (T < NT - 2) gll(aP + ko, ldst + f);
        af[2] = *(const int32x4*)(ls + aoff + 2048);
        af[3] = *(const int32x4*)(ls + aoff + 3072);
        __builtin_amdgcn_s_setprio(1);
#pragma unroll
        for (int m = 0; m < 2; ++m)
#pragma unroll
            for (int n = 0; n < 4; ++n)
                acc[m][n] = __builtin_amdgcn_mfma_i32_16x16x64_i8(af[m], bf[n], acc[m][n], 0, 0, 0);
        __builtin_amdgcn_s_setprio(0);
        if (T < NT - 2) { gll(b0P + ko, ldst + 8192 + f); gll(b1P + ko, ldst + 16384 + f); }
        __builtin_amdgcn_s_setprio(1);
#pragma unroll
        for (int m = 2; m < 4; ++m)
#pragma unroll
            for (int n = 0; n < 4; ++n)
                acc[m][n] = __builtin_amdgcn_mfma_i32_16x16x64_i8(af[m], bf[n], acc[m][n], 0, 0, 0);
        __builtin_amdgcn_s_setprio(0);
        // gate tile T+1's 3 glls (issued during T-1): steady outstanding = 6 -> wait 3
        if (T < NT - 2) {
            asm volatile("s_waitcnt vmcnt(3)" ::: "memory");
            __builtin_amdgcn_s_barrier();
        } else if (T == NT - 2) {
            asm volatile("s_waitcnt vmcnt(0)" ::: "memory");
            __builtin_amdgcn_s_barrier();
        }
        s = (s == 2) ? 0 : s + 1;
        d = (d == 2) ? 0 : d + 1;
    }

    // epilogue: dequant + store (C layout: col=lane&15, row=(lane>>4)*4+reg)
    const float alpha = *alpha_p;
#pragma unroll
    for (int mi = 0; mi < 4; ++mi) {
        int rbase = row0 + wm * 64 + mi * 16 + ((lane >> 4) << 2);
#pragma unroll
        for (int r = 0; r < 4; ++r) {
            int row = rbase + r;
            float scale = alpha * beta[row];
#pragma unroll
            for (int n = 0; n < 4; ++n) {
                int col = col0 + wn * 64 + n * 16 + (lane & 15);
                out[(size_t)row * OUT_DIM + col] = (float)acc[mi][n][r] * scale;
            }
        }
    }
}

extern "C" void kernel_launch(void* const* d_in, const int* in_sizes, int n_in,
                              void* d_out, int out_size, void* d_ws, size_t ws_size,
                              hipStream_t stream) {
    const float* x = (const float*)d_in[0];
    const float* w = (const float*)d_in[1];
    float* out = (float*)d_out;

    const int tokens = in_sizes[0] / IN_DIM;          // 16384
    const int n_w = in_sizes[1];                      // 4194304
    const int n_w4 = n_w / 4;

    char* ws = (char*)d_ws;
    double* d_sum = (double*)ws;                      // 8 B
    float* d_alpha = (float*)(ws + 8);                // 4 B
    float* d_beta = (float*)(ws + 256);               // tokens * 4 B
    signed char* d_wq = (signed char*)(ws + 256 + 65536);
    signed char* d_xq = d_wq + (size_t)n_w;

    hipMemsetAsync(d_ws, 0, 16, stream);

    absum_kernel<<<1024, 256, 0, stream>>>(w, d_sum, n_w4);
    quantw_kernel<<<(n_w4 + 255) / 256, 256, 0, stream>>>(w, d_sum, d_wq, d_alpha, n_w4);
    quantx_kernel<<<2048, 256, 0, stream>>>(x, d_xq, d_beta, tokens);

    hipFuncSetAttribute((const void*)gemm_kernel,
                        hipFuncAttributeMaxDynamicSharedMemorySize, LDS_SZ);

    dim3 grid(OUT_DIM / BN, tokens / BM);             // (8, 128)
    gemm_kernel<<<grid, 512, LDS_SZ, stream>>>(d_xq, d_wq, d_beta, d_alpha, out);
}

// Round 4
// 156.402 us; speedup vs baseline: 1.1074x; 1.1074x over previous
//
#include <hip/hip_runtime.h>

#define IN_DIM 2048
#define OUT_DIM 2048
#define EPS 1e-8f

#define BK 64                  // i8 bytes per K-tile
#define NT (IN_DIM / BK)       // 32 K-tiles
#define SLOT 32768             // A 16K + B 16K per slot (granule-major 32rx32k)
#define LDS_SZ 98304           // 3 slots

using int32x4  = __attribute__((ext_vector_type(4))) int;
using int32x16 = __attribute__((ext_vector_type(16))) int;

// ---------------- Kernel 1: sum of |W| ----------------
__global__ __launch_bounds__(256) void absum_kernel(const float* __restrict__ w,
                                                    double* __restrict__ sum, int n4) {
    int tid = blockIdx.x * blockDim.x + threadIdx.x;
    int stride = gridDim.x * blockDim.x;
    float s = 0.f;
    for (int i = tid; i < n4; i += stride) {
        float4 v = ((const float4*)w)[i];
        s += fabsf(v.x) + fabsf(v.y) + fabsf(v.z) + fabsf(v.w);
    }
    for (int off = 32; off; off >>= 1) s += __shfl_down(s, off);
    __shared__ float wsum[4];
    int lane = threadIdx.x & 63, wave = threadIdx.x >> 6;
    if (lane == 0) wsum[wave] = s;
    __syncthreads();
    if (threadIdx.x == 0) {
        double t = (double)wsum[0] + (double)wsum[1] + (double)wsum[2] + (double)wsum[3];
        atomicAdd(sum, t);
    }
}

// ---------------- Kernel 2: quantize W to ternary int8 ----------------
__global__ __launch_bounds__(256) void quantw_kernel(const float* __restrict__ w,
                                                     const double* __restrict__ sumptr,
                                                     signed char* __restrict__ wq,
                                                     float* __restrict__ alpha_out, int n4) {
    float alpha = fmaxf((float)(*sumptr * (1.0 / (double)(IN_DIM * OUT_DIM))), EPS);
    int i = blockIdx.x * blockDim.x + threadIdx.x;
    if (i == 0) *alpha_out = alpha;
    if (i >= n4) return;
    float4 v = ((const float4*)w)[i];
    char4 q;
    q.x = (signed char)fminf(fmaxf(rintf(v.x / alpha), -1.f), 1.f);
    q.y = (signed char)fminf(fmaxf(rintf(v.y / alpha), -1.f), 1.f);
    q.z = (signed char)fminf(fmaxf(rintf(v.z / alpha), -1.f), 1.f);
    q.w = (signed char)fminf(fmaxf(rintf(v.w / alpha), -1.f), 1.f);
    ((char4*)wq)[i] = q;
}

// ---------------- Kernel 3: per-token beta + quantize x ----------------
__global__ __launch_bounds__(256) void quantx_kernel(const float* __restrict__ x,
                                                     signed char* __restrict__ xq,
                                                     float* __restrict__ beta_arr,
                                                     int tokens) {
    const int tid = threadIdx.x;
    const int lane = tid & 63, wave = tid >> 6;
    __shared__ float wmax[4];
    for (int t = blockIdx.x; t < tokens; t += gridDim.x) {
        const float4* row = (const float4*)(x + (size_t)t * IN_DIM);
        float4 v0 = row[tid];
        float4 v1 = row[tid + 256];
        float m = fmaxf(fmaxf(fmaxf(fabsf(v0.x), fabsf(v0.y)), fmaxf(fabsf(v0.z), fabsf(v0.w))),
                        fmaxf(fmaxf(fabsf(v1.x), fabsf(v1.y)), fmaxf(fabsf(v1.z), fabsf(v1.w))));
        for (int off = 32; off; off >>= 1) m = fmaxf(m, __shfl_xor(m, off));
        if (lane == 0) wmax[wave] = m;
        __syncthreads();
        m = fmaxf(fmaxf(wmax[0], wmax[1]), fmaxf(wmax[2], wmax[3]));
        float beta = fmaxf(m * (1.f / 127.f), EPS);
        if (tid == 0) beta_arr[t] = beta;
        char4 q0, q1;
        q0.x = (signed char)fminf(fmaxf(rintf(v0.x / beta), -127.f), 127.f);
        q0.y = (signed char)fminf(fmaxf(rintf(v0.y / beta), -127.f), 127.f);
        q0.z = (signed char)fminf(fmaxf(rintf(v0.z / beta), -127.f), 127.f);
        q0.w = (signed char)fminf(fmaxf(rintf(v0.w / beta), -127.f), 127.f);
        q1.x = (signed char)fminf(fmaxf(rintf(v1.x / beta), -127.f), 127.f);
        q1.y = (signed char)fminf(fmaxf(rintf(v1.y / beta), -127.f), 127.f);
        q1.z = (signed char)fminf(fmaxf(rintf(v1.z / beta), -127.f), 127.f);
        q1.w = (signed char)fminf(fmaxf(rintf(v1.w / beta), -127.f), 127.f);
        char4* orow = (char4*)(xq + (size_t)t * IN_DIM);
        orow[tid] = q0;
        orow[tid + 256] = q1;
        __syncthreads();
    }
}

// ---------------- GEMM helper ----------------
__device__ __forceinline__ void gll(const signed char* g, signed char* l) {
    __builtin_amdgcn_global_load_lds((const __attribute__((address_space(1))) void*)g,
        (__attribute__((address_space(3))) void*)l, 16, 0, 0);
}

// ---------------- Kernel 4: int8 MFMA GEMM, 32x32x32 shape, 256x256 tile ----------------
// 512 threads = 8 waves (2M x 4N); wave-tile 128x64 via 4x2 of 32x32; acc[4][2]x16 = 128 regs.
// v_mfma_i32_32x32x32_i8: 2x ops/instruction vs 16x16x64 -> HALF the MFMA instructions and
// half the lgkm gate events per K-tile at the same frag-byte traffic; rate 4404 vs 3944 TOPS.
// LDS slot 32 KiB: A @0 (ks0 0-8K, ks1 8-16K), B @16K (same); granule = 32 rows x 32 k-bytes,
// in-granule byte = l*16 with row=l&31, k-half=l>>5 -> lane-linear (conflict-free ds_read_b128
// at base+lane*16, and legal linear gll dest with per-lane pre-swizzled global source).
// 3-slot rotation, stage T+2 (4 glls/tile), gate vmcnt(4), 1 barrier per K-tile.
// Grid (64,8) row-fastest: consecutive blocks share the B-panel -> FETCH ~49 MB (round-0 level).
__global__ __launch_bounds__(512, 2) void gemm_kernel(const signed char* __restrict__ xq,
                                                      const signed char* __restrict__ wq,
                                                      const float* __restrict__ beta,
                                                      const float* __restrict__ alpha_p,
                                                      float* __restrict__ out) {
    extern __shared__ signed char lds[];   // 98304
    const int tid = threadIdx.x;
    const int lane = tid & 63;
    const int wave = tid >> 6;
    const int wm = wave >> 2;              // 0..1 (row half: 128 rows)
    const int wn = wave & 3;               // 0..3 (col quarter: 64 cols)
    const int row0 = blockIdx.x * 256;
    const int col0 = blockIdx.y * 256;

    // staging: thread t writes LDS [t*16, +16) per region-half; granule rg=t>>6;
    // source element: row = rg*32 + (lane&31), k-offset (lane>>5)*16 within the 32-byte ks group
    const int f = tid * 16;
    const int srow = ((tid >> 6) << 5) + (lane & 31);   // 0..255
    const int skh = (lane >> 5) << 4;                   // 0 or 16
    const signed char* aS = xq + (size_t)(row0 + srow) * IN_DIM + skh;
    const signed char* bS = wq + (size_t)(col0 + srow) * IN_DIM + skh;

    // fragment addressing: frag = 1 KiB granule, lane-linear
    const int l16 = lane * 16;
    const int aoff = (wm << 12) + l16;             // + m*1024 + ks*8192
    const int boff = 16384 + (wn << 11) + l16;     // + n*1024 + ks*8192

    int32x16 acc[4][2] = {};

    // prologue: stage tiles 0,1 into slots 0,1 (4 glls each: A ks0, A ks1, B ks0, B ks1)
    gll(aS,       lds + f);          gll(aS + 32,  lds + 8192 + f);
    gll(bS,       lds + 16384 + f);  gll(bS + 32,  lds + 24576 + f);
    gll(aS + 64,  lds + SLOT + f);          gll(aS + 96,  lds + SLOT + 8192 + f);
    gll(bS + 64,  lds + SLOT + 16384 + f);  gll(bS + 96,  lds + SLOT + 24576 + f);
    asm volatile("s_waitcnt vmcnt(4)" ::: "memory");   // tile 0's 4 landed
    __builtin_amdgcn_s_barrier();

    int s = 0, d = 2;   // read slot = T%3, stage dest = (T+2)%3
    for (int T = 0; T < NT; ++T) {
        const signed char* ls = lds + s * SLOT;
        signed char* ldst = lds + d * SLOT;
        const size_t ko = (size_t)(T + 2) * BK;
        int32x4 a0[4], a1[4], b0[2], b1[2];
#pragma unroll
        for (int m = 0; m < 4; ++m) a0[m] = *(const int32x4*)(ls + aoff + m * 1024);
#pragma unroll
        for (int n = 0; n < 2; ++n) b0[n] = *(const int32x4*)(ls + boff + n * 1024);
        if (T < NT - 2) { gll(aS + ko, ldst + f); gll(aS + ko + 32, ldst + 8192 + f); }
#pragma unroll
        for (int m = 0; m < 4; ++m) a1[m] = *(const int32x4*)(ls + aoff + 8192 + m * 1024);
#pragma unroll
        for (int n = 0; n < 2; ++n) b1[n] = *(const int32x4*)(ls + boff + 8192 + n * 1024);
        __builtin_amdgcn_s_setprio(1);
#pragma unroll
        for (int m = 0; m < 4; ++m)
#pragma unroll
            for (int n = 0; n < 2; ++n)
                acc[m][n] = __builtin_amdgcn_mfma_i32_32x32x32_i8(a0[m], b0[n], acc[m][n], 0, 0, 0);
        __builtin_amdgcn_s_setprio(0);
        if (T < NT - 2) { gll(bS + ko, ldst + 16384 + f); gll(bS + ko + 32, ldst + 24576 + f); }
        __builtin_amdgcn_s_setprio(1);
#pragma unroll
        for (int m = 0; m < 4; ++m)
#pragma unroll
            for (int n = 0; n < 2; ++n)
                acc[m][n] = __builtin_amdgcn_mfma_i32_32x32x32_i8(a1[m], b1[n], acc[m][n], 0, 0, 0);
        __builtin_amdgcn_s_setprio(0);
        // gate tile T+1's 4 glls (issued during T-1); keep T+2's 4 in flight
        if (T < NT - 2) {
            asm volatile("s_waitcnt vmcnt(4)" ::: "memory");
            __builtin_amdgcn_s_barrier();
        } else if (T == NT - 2) {
            asm volatile("s_waitcnt vmcnt(0)" ::: "memory");
            __builtin_amdgcn_s_barrier();
        }
        s = (s == 2) ? 0 : s + 1;
        d = (d == 2) ? 0 : d + 1;
    }

    // epilogue: dequant + store.
    // 32x32 C layout (m74/m101, dtype-independent): col = lane&31,
    // row = (reg&3) + 8*(reg>>2) + 4*(lane>>5)
    const float alpha = *alpha_p;
#pragma unroll
    for (int m = 0; m < 4; ++m) {
        const int rb = row0 + wm * 128 + m * 32 + ((lane >> 5) << 2);
#pragma unroll
        for (int n = 0; n < 2; ++n) {
            const int col = col0 + wn * 64 + n * 32 + (lane & 31);
#pragma unroll
            for (int reg = 0; reg < 16; ++reg) {
                const int row = rb + (reg & 3) + ((reg >> 2) << 3);
                out[(size_t)row * OUT_DIM + col] = (float)acc[m][n][reg] * (alpha * beta[row]);
            }
        }
    }
}

extern "C" void kernel_launch(void* const* d_in, const int* in_sizes, int n_in,
                              void* d_out, int out_size, void* d_ws, size_t ws_size,
                              hipStream_t stream) {
    const float* x = (const float*)d_in[0];
    const float* w = (const float*)d_in[1];
    float* out = (float*)d_out;

    const int tokens = in_sizes[0] / IN_DIM;          // 16384
    const int n_w = in_sizes[1];                      // 4194304
    const int n_w4 = n_w / 4;

    char* ws = (char*)d_ws;
    double* d_sum = (double*)ws;                      // 8 B
    float* d_alpha = (float*)(ws + 8);                // 4 B
    float* d_beta = (float*)(ws + 256);               // tokens * 4 B
    signed char* d_wq = (signed char*)(ws + 256 + 65536);
    signed char* d_xq = d_wq + (size_t)n_w;

    hipMemsetAsync(d_ws, 0, 16, stream);

    absum_kernel<<<1024, 256, 0, stream>>>(w, d_sum, n_w4);
    quantw_kernel<<<(n_w4 + 255) / 256, 256, 0, stream>>>(w, d_sum, d_wq, d_alpha, n_w4);
    quantx_kernel<<<2048, 256, 0, stream>>>(x, d_xq, d_beta, tokens);

    hipFuncSetAttribute((const void*)gemm_kernel,
                        hipFuncAttributeMaxDynamicSharedMemorySize, LDS_SZ);

    dim3 grid(16384 / 256, OUT_DIM / 256);            // (64, 8) row-fastest
    gemm_kernel<<<grid, 512, LDS_SZ, stream>>>(d_xq, d_wq, d_beta, d_alpha, out);
}

// Round 5
// 149.550 us; speedup vs baseline: 1.1581x; 1.0458x over previous
//
#include <hip/hip_runtime.h>

#define IN_DIM 2048
#define OUT_DIM 2048
#define EPS 1e-8f

#define BK 128                 // i8 bytes per K-tile
#define NKT (IN_DIM / BK)      // 16 K-tiles
#define HALF 16384             // half-tile: 256 rows x 64 B (granule-major)
// LDS map (131072 B): A ks0 @ 0,16K | A ks1 @ 32K,48K | B ks0 @ 64K,80K | B ks1 @ 96K,112K

using int32x4 = __attribute__((ext_vector_type(4))) int;

// ---------------- Kernel 1: sum of |W| ----------------
__global__ __launch_bounds__(256) void absum_kernel(const float* __restrict__ w,
                                                    double* __restrict__ sum, int n4) {
    int tid = blockIdx.x * blockDim.x + threadIdx.x;
    int stride = gridDim.x * blockDim.x;
    float s = 0.f;
    for (int i = tid; i < n4; i += stride) {
        float4 v = ((const float4*)w)[i];
        s += fabsf(v.x) + fabsf(v.y) + fabsf(v.z) + fabsf(v.w);
    }
    for (int off = 32; off; off >>= 1) s += __shfl_down(s, off);
    __shared__ float wsum[4];
    int lane = threadIdx.x & 63, wave = threadIdx.x >> 6;
    if (lane == 0) wsum[wave] = s;
    __syncthreads();
    if (threadIdx.x == 0) {
        double t = (double)wsum[0] + (double)wsum[1] + (double)wsum[2] + (double)wsum[3];
        atomicAdd(sum, t);
    }
}

// ---------------- Kernel 2: quantize W to ternary int8 ----------------
__global__ __launch_bounds__(256) void quantw_kernel(const float* __restrict__ w,
                                                     const double* __restrict__ sumptr,
                                                     signed char* __restrict__ wq,
                                                     float* __restrict__ alpha_out, int n4) {
    float alpha = fmaxf((float)(*sumptr * (1.0 / (double)(IN_DIM * OUT_DIM))), EPS);
    int i = blockIdx.x * blockDim.x + threadIdx.x;
    if (i == 0) *alpha_out = alpha;
    if (i >= n4) return;
    float4 v = ((const float4*)w)[i];
    char4 q;
    q.x = (signed char)fminf(fmaxf(rintf(v.x / alpha), -1.f), 1.f);
    q.y = (signed char)fminf(fmaxf(rintf(v.y / alpha), -1.f), 1.f);
    q.z = (signed char)fminf(fmaxf(rintf(v.z / alpha), -1.f), 1.f);
    q.w = (signed char)fminf(fmaxf(rintf(v.w / alpha), -1.f), 1.f);
    ((char4*)wq)[i] = q;
}

// ---------------- Kernel 3: per-token beta + quantize x (WAVE per token) ----------------
// One 64-lane wave owns one 2048-float row: 8 float4/lane, reduce via 6 shfl_xor,
// no LDS, no barriers -> 4 independent tokens in flight per block, pure streaming.
__global__ __launch_bounds__(256) void quantx_kernel(const float* __restrict__ x,
                                                     signed char* __restrict__ xq,
                                                     float* __restrict__ beta_arr,
                                                     int tokens) {
    const int lane = threadIdx.x & 63;
    const int wave = threadIdx.x >> 6;
    const int t = blockIdx.x * 4 + wave;          // 4096 blocks x 4 waves = 16384
    if (t >= tokens) return;

    const float4* row = (const float4*)(x + (size_t)t * IN_DIM);
    float4 v[8];
    float m = 0.f;
#pragma unroll
    for (int j = 0; j < 8; ++j) {
        v[j] = row[lane + 64 * j];
        m = fmaxf(m, fmaxf(fmaxf(fabsf(v[j].x), fabsf(v[j].y)),
                           fmaxf(fabsf(v[j].z), fabsf(v[j].w))));
    }
#pragma unroll
    for (int off = 32; off; off >>= 1) m = fmaxf(m, __shfl_xor(m, off));
    const float beta = fmaxf(m * (1.f / 127.f), EPS);
    if (lane == 0) beta_arr[t] = beta;

    char4* orow = (char4*)(xq + (size_t)t * IN_DIM);
#pragma unroll
    for (int j = 0; j < 8; ++j) {
        char4 q;
        q.x = (signed char)fminf(fmaxf(rintf(v[j].x / beta), -127.f), 127.f);
        q.y = (signed char)fminf(fmaxf(rintf(v[j].y / beta), -127.f), 127.f);
        q.z = (signed char)fminf(fmaxf(rintf(v[j].z / beta), -127.f), 127.f);
        q.w = (signed char)fminf(fmaxf(rintf(v[j].w / beta), -127.f), 127.f);
        orow[lane + 64 * j] = q;
    }
}

// ---------------- GEMM helpers ----------------
__device__ __forceinline__ void gll(const signed char* g, signed char* l) {
    __builtin_amdgcn_global_load_lds((const __attribute__((address_space(1))) void*)g,
        (__attribute__((address_space(3))) void*)l, 16, 0, 0);
}

#define CLUSTER(BASE, AF)                                                                      \
    __builtin_amdgcn_s_setprio(1);                                                             \
    _Pragma("unroll")                                                                          \
    for (int m_ = 0; m_ < 4; ++m_)                                                             \
        _Pragma("unroll")                                                                      \
        for (int n_ = 0; n_ < 4; ++n_)                                                         \
            acc[(BASE) + m_][n_] = __builtin_amdgcn_mfma_i32_16x16x64_i8(                      \
                AF[m_], bf[n_], acc[(BASE) + m_][n_], 0, 0, 0);                                \
    __builtin_amdgcn_s_setprio(0);

// One K-tile, NO lgkm drains (compiler emits counted lgkm at MFMA use sites so
// trailing reads drain under MFMA execution). Structure:
//   R1(8 reads) G1 R2(4 reads) C1 G2 C2 [vmcnt(4); barrier]   <- Ah1/Bh1(T) landed
//   R3(8 reads) G3 R4(4 reads) C3 G4 C4 [vmcnt(4); barrier]   <- Ah0/Bh0(T+1) landed
// Stage order per tile: G1=Ah0(T+1) G2=Bh0(T+1) G3=Ah1(T+1) G4=Bh1(T+1) (2 gll each).
// Per-wave vmcnt(4)+barrier gate => all waves' older gll landed (cross-wave safe).
// Never vmcnt(0) in main loop; tail drains.
template<bool STG, bool TAIL>
__device__ __forceinline__ void ktile(int T, signed char* lds, int32x4 (&acc)[8][4],
                                      int aoff, int boff, int f0, int f1,
                                      const signed char* a0, const signed char* a1,
                                      const signed char* b0, const signed char* b1) {
    const int s = (T & 1) * HALF;
    const int d = ((T + 1) & 1) * HALF;
    const size_t ko = (size_t)(T + 1) * BK;
    int32x4 af0[4], af1[4], bf[4];

    // ---- half ks0 ----
#pragma unroll
    for (int m = 0; m < 4; ++m) af0[m] = *(const int32x4*)(lds + s + aoff + m * 1024);
#pragma unroll
    for (int n = 0; n < 4; ++n) bf[n] = *(const int32x4*)(lds + 65536 + s + boff + n * 1024);
    if constexpr (STG) { gll(a0 + ko, lds + d + f0); gll(a1 + ko, lds + d + f1); }
#pragma unroll
    for (int m = 0; m < 4; ++m) af1[m] = *(const int32x4*)(lds + s + aoff + 4096 + m * 1024);
    CLUSTER(0, af0)
    if constexpr (STG) { gll(b0 + ko, lds + 65536 + d + f0); gll(b1 + ko, lds + 65536 + d + f1); }
    CLUSTER(4, af1)
    if constexpr (TAIL) asm volatile("s_waitcnt vmcnt(0)" ::: "memory");
    else                asm volatile("s_waitcnt vmcnt(4)" ::: "memory");
    __builtin_amdgcn_s_barrier();

    // ---- half ks1 ----
#pragma unroll
    for (int m = 0; m < 4; ++m) af0[m] = *(const int32x4*)(lds + 32768 + s + aoff + m * 1024);
#pragma unroll
    for (int n = 0; n < 4; ++n) bf[n] = *(const int32x4*)(lds + 98304 + s + boff + n * 1024);
    if constexpr (STG) { gll(a0 + ko + 64, lds + 32768 + d + f0); gll(a1 + ko + 64, lds + 32768 + d + f1); }
#pragma unroll
    for (int m = 0; m < 4; ++m) af1[m] = *(const int32x4*)(lds + 32768 + s + aoff + 4096 + m * 1024);
    CLUSTER(0, af0)
    if constexpr (STG) { gll(b0 + ko + 64, lds + 98304 + d + f0); gll(b1 + ko + 64, lds + 98304 + d + f1); }
    CLUSTER(4, af1)
    if constexpr (!TAIL) {
        asm volatile("s_waitcnt vmcnt(4)" ::: "memory");
        __builtin_amdgcn_s_barrier();
    }
}

// ---------------- Kernel 4: int8 MFMA GEMM, 256x256 tile ----------------
// 512 threads = 8 waves (2M x 4N); wave-tile 128x64; acc[8][4] (128 VGPR).
// Granule-major half-tiles (0 bank conflicts), dbuf-2 slots, counted vmcnt(4),
// compiler-counted lgkm (no drains), 2 barriers per K-tile.  [round-0 verbatim: 91.1 us]
__global__ __launch_bounds__(512, 2) void gemm_kernel(const signed char* __restrict__ xq,
                                                      const signed char* __restrict__ wq,
                                                      const float* __restrict__ beta,
                                                      const float* __restrict__ alpha_p,
                                                      float* __restrict__ out) {
    extern __shared__ signed char lds[];   // 131072
    const int tid = threadIdx.x;
    const int lane = tid & 63;
    const int wave = tid >> 6;
    const int wm = wave >> 2;              // 0..1
    const int wn = wave & 3;               // 0..3
    const int row0 = blockIdx.x * 256;
    const int col0 = blockIdx.y * 256;

    // staging: 2 x 16B chunks per half-tile per thread (granule-major:
    // addr = g*1024 + kg*256 + r*16; row = g*16+r, kg = 16B k-group)
    const int f0 = tid * 16;
    const int f1 = f0 + 8192;
    const int g0 = f0 >> 10, kg0 = (f0 >> 8) & 3, r0 = (f0 >> 4) & 15;
    const int g1 = f1 >> 10, kg1 = (f1 >> 8) & 3, r1 = (f1 >> 4) & 15;
    const signed char* a0 = xq + (size_t)(row0 + g0 * 16 + r0) * IN_DIM + kg0 * 16;
    const signed char* a1 = xq + (size_t)(row0 + g1 * 16 + r1) * IN_DIM + kg1 * 16;
    const signed char* b0 = wq + (size_t)(col0 + g0 * 16 + r0) * IN_DIM + kg0 * 16;
    const signed char* b1 = wq + (size_t)(col0 + g1 * 16 + r1) * IN_DIM + kg1 * 16;

    const int kr = (lane >> 4) * 256 + (lane & 15) * 16;
    const int aoff = wm * 8192 + kr;       // + mh*4096 + m*1024
    const int boff = wn * 4096 + kr;       // + n*1024

    int32x4 acc[8][4] = {};

    // prologue: tile 0's four half-tiles into slot 0 (consumption order)
    gll(a0, lds + f0);              gll(a1, lds + f1);               // Ah0
    gll(b0, lds + 65536 + f0);      gll(b1, lds + 65536 + f1);       // Bh0
    gll(a0 + 64, lds + 32768 + f0); gll(a1 + 64, lds + 32768 + f1);  // Ah1
    gll(b0 + 64, lds + 98304 + f0); gll(b1 + 64, lds + 98304 + f1);  // Bh1
    asm volatile("s_waitcnt vmcnt(4)" ::: "memory");                 // Ah0,Bh0 landed
    __builtin_amdgcn_s_barrier();

    for (int T = 0; T < NKT - 1; ++T)
        ktile<true, false>(T, lds, acc, aoff, boff, f0, f1, a0, a1, b0, b1);
    ktile<false, true>(NKT - 1, lds, acc, aoff, boff, f0, f1, a0, a1, b0, b1);

    // epilogue: dequant + store
    const float alpha = *alpha_p;
#pragma unroll
    for (int mi = 0; mi < 8; ++mi) {
        int rbase = row0 + wm * 128 + mi * 16 + ((lane >> 4) << 2);
#pragma unroll
        for (int r = 0; r < 4; ++r) {
            int row = rbase + r;
            float scale = alpha * beta[row];
#pragma unroll
            for (int n = 0; n < 4; ++n) {
                int col = col0 + wn * 64 + n * 16 + (lane & 15);
                out[(size_t)row * OUT_DIM + col] = (float)acc[mi][n][r] * scale;
            }
        }
    }
}

extern "C" void kernel_launch(void* const* d_in, const int* in_sizes, int n_in,
                              void* d_out, int out_size, void* d_ws, size_t ws_size,
                              hipStream_t stream) {
    const float* x = (const float*)d_in[0];
    const float* w = (const float*)d_in[1];
    float* out = (float*)d_out;

    const int tokens = in_sizes[0] / IN_DIM;          // 16384
    const int n_w = in_sizes[1];                      // 4194304
    const int n_w4 = n_w / 4;

    char* ws = (char*)d_ws;
    double* d_sum = (double*)ws;                      // 8 B
    float* d_alpha = (float*)(ws + 8);                // 4 B
    float* d_beta = (float*)(ws + 256);               // tokens * 4 B
    signed char* d_wq = (signed char*)(ws + 256 + 65536);
    signed char* d_xq = d_wq + (size_t)n_w;

    hipMemsetAsync(d_ws, 0, 16, stream);

    absum_kernel<<<1024, 256, 0, stream>>>(w, d_sum, n_w4);
    quantw_kernel<<<(n_w4 + 255) / 256, 256, 0, stream>>>(w, d_sum, d_wq, d_alpha, n_w4);
    quantx_kernel<<<(tokens + 3) / 4, 256, 0, stream>>>(x, d_xq, d_beta, tokens);

    hipFuncSetAttribute((const void*)gemm_kernel,
                        hipFuncAttributeMaxDynamicSharedMemorySize, 131072);

    dim3 grid(16384 / 256, OUT_DIM / 256);            // (64, 8)
    gemm_kernel<<<grid, 512, 131072, stream>>>(d_xq, d_wq, d_beta, d_alpha, out);
}

// Round 6
// 147.809 us; speedup vs baseline: 1.1718x; 1.0118x over previous
//
#include <hip/hip_runtime.h>

#define IN_DIM 2048
#define OUT_DIM 2048
#define EPS 1e-8f

#define BK 128                 // i8 bytes per K-tile
#define NKT (IN_DIM / BK)      // 16 K-tiles
#define HALF 16384             // half-tile: 256 rows x 64 B (granule-major)
// LDS map (131072 B): A ks0 @ 0,16K | A ks1 @ 32K,48K | B ks0 @ 64K,80K | B ks1 @ 96K,112K

using int32x4 = __attribute__((ext_vector_type(4))) int;

// ---------------- Kernel 1: sum of |W| ----------------
__global__ __launch_bounds__(256) void absum_kernel(const float* __restrict__ w,
                                                    double* __restrict__ sum, int n4) {
    int tid = blockIdx.x * blockDim.x + threadIdx.x;
    int stride = gridDim.x * blockDim.x;
    float s = 0.f;
    for (int i = tid; i < n4; i += stride) {
        float4 v = ((const float4*)w)[i];
        s += fabsf(v.x) + fabsf(v.y) + fabsf(v.z) + fabsf(v.w);
    }
    for (int off = 32; off; off >>= 1) s += __shfl_down(s, off);
    __shared__ float wsum[4];
    int lane = threadIdx.x & 63, wave = threadIdx.x >> 6;
    if (lane == 0) wsum[wave] = s;
    __syncthreads();
    if (threadIdx.x == 0) {
        double t = (double)wsum[0] + (double)wsum[1] + (double)wsum[2] + (double)wsum[3];
        atomicAdd(sum, t);
    }
}

// ---------------- Kernel 2: quantize W to ternary int8 ----------------
__global__ __launch_bounds__(256) void quantw_kernel(const float* __restrict__ w,
                                                     const double* __restrict__ sumptr,
                                                     signed char* __restrict__ wq,
                                                     float* __restrict__ alpha_out, int n4) {
    float alpha = fmaxf((float)(*sumptr * (1.0 / (double)(IN_DIM * OUT_DIM))), EPS);
    int i = blockIdx.x * blockDim.x + threadIdx.x;
    if (i == 0) *alpha_out = alpha;
    if (i >= n4) return;
    float4 v = ((const float4*)w)[i];
    char4 q;
    q.x = (signed char)fminf(fmaxf(rintf(v.x / alpha), -1.f), 1.f);
    q.y = (signed char)fminf(fmaxf(rintf(v.y / alpha), -1.f), 1.f);
    q.z = (signed char)fminf(fmaxf(rintf(v.z / alpha), -1.f), 1.f);
    q.w = (signed char)fminf(fmaxf(rintf(v.w / alpha), -1.f), 1.f);
    ((char4*)wq)[i] = q;
}

// ---------------- Kernel 3: per-token beta + quantize x (WAVE per token) ----------------
__global__ __launch_bounds__(256) void quantx_kernel(const float* __restrict__ x,
                                                     signed char* __restrict__ xq,
                                                     float* __restrict__ beta_arr,
                                                     int tokens) {
    const int lane = threadIdx.x & 63;
    const int wave = threadIdx.x >> 6;
    const int t = blockIdx.x * 4 + wave;
    if (t >= tokens) return;

    const float4* row = (const float4*)(x + (size_t)t * IN_DIM);
    float4 v[8];
    float m = 0.f;
#pragma unroll
    for (int j = 0; j < 8; ++j) {
        v[j] = row[lane + 64 * j];
        m = fmaxf(m, fmaxf(fmaxf(fabsf(v[j].x), fabsf(v[j].y)),
                           fmaxf(fabsf(v[j].z), fabsf(v[j].w))));
    }
#pragma unroll
    for (int off = 32; off; off >>= 1) m = fmaxf(m, __shfl_xor(m, off));
    const float beta = fmaxf(m * (1.f / 127.f), EPS);
    if (lane == 0) beta_arr[t] = beta;

    char4* orow = (char4*)(xq + (size_t)t * IN_DIM);
#pragma unroll
    for (int j = 0; j < 8; ++j) {
        char4 q;
        q.x = (signed char)fminf(fmaxf(rintf(v[j].x / beta), -127.f), 127.f);
        q.y = (signed char)fminf(fmaxf(rintf(v[j].y / beta), -127.f), 127.f);
        q.z = (signed char)fminf(fmaxf(rintf(v[j].z / beta), -127.f), 127.f);
        q.w = (signed char)fminf(fmaxf(rintf(v[j].w / beta), -127.f), 127.f);
        orow[lane + 64 * j] = q;
    }
}

// ---------------- GEMM helpers ----------------
__device__ __forceinline__ void gll(const signed char* g, signed char* l) {
    __builtin_amdgcn_global_load_lds((const __attribute__((address_space(1))) void*)g,
        (__attribute__((address_space(3))) void*)l, 16, 0, 0);
}

// 16 MFMAs: acc[MB+m][NB+n] += af[MB+m] * bf[NB+n]
#define CLUSTER(MB, NB)                                                                        \
    __builtin_amdgcn_s_setprio(1);                                                             \
    _Pragma("unroll")                                                                          \
    for (int m_ = 0; m_ < 4; ++m_)                                                             \
        _Pragma("unroll")                                                                      \
        for (int n_ = 0; n_ < 4; ++n_)                                                         \
            acc[(MB) + m_][(NB) + n_] = __builtin_amdgcn_mfma_i32_16x16x64_i8(                 \
                af[(MB) + m_], bf[(NB) + n_], acc[(MB) + m_][(NB) + n_], 0, 0, 0);             \
    __builtin_amdgcn_s_setprio(0);

// One K-tile, 8x8 register blocking (wave-tile 128x128): per half, 16 ds_read_b128
// feed 64 MFMAs (0.25 reads/MFMA vs 0.375 before -> -33% LDS-read cycles, the shared-
// pipe convoy that co-limited with MFMA). 4 waves, 1/SIMD; reads issued up front so
// counted lgkm drains under cluster 1; glls issued a tile ahead so vmcnt(8) is cheap.
template<bool STG, bool TAIL>
__device__ __forceinline__ void ktile(int T, signed char* lds, int32x4 (&acc)[8][8],
                                      int aoff, int boff, int f,
                                      const signed char* (&aP)[4], const signed char* (&bP)[4]) {
    const int s = (T & 1) * HALF;
    const int d = ((T + 1) & 1) * HALF;
    const size_t ko = (size_t)(T + 1) * BK;
    int32x4 af[8], bf[8];

    // ---- half ks0 ----
#pragma unroll
    for (int m = 0; m < 4; ++m) af[m] = *(const int32x4*)(lds + s + aoff + m * 1024);
#pragma unroll
    for (int n = 0; n < 4; ++n) bf[n] = *(const int32x4*)(lds + 65536 + s + boff + n * 1024);
    if constexpr (STG) {
#pragma unroll
        for (int c = 0; c < 4; ++c) gll(aP[c] + ko, lds + d + f + c * 4096);
    }
#pragma unroll
    for (int m = 0; m < 4; ++m) af[4 + m] = *(const int32x4*)(lds + s + aoff + 4096 + m * 1024);
#pragma unroll
    for (int n = 0; n < 4; ++n) bf[4 + n] = *(const int32x4*)(lds + 65536 + s + boff + 4096 + n * 1024);
    CLUSTER(0, 0)
    if constexpr (STG) {
#pragma unroll
        for (int c = 0; c < 4; ++c) gll(bP[c] + ko, lds + 65536 + d + f + c * 4096);
    }
    CLUSTER(0, 4)
    CLUSTER(4, 0)
    CLUSTER(4, 4)
    if constexpr (TAIL) asm volatile("s_waitcnt vmcnt(0)" ::: "memory");
    else                asm volatile("s_waitcnt vmcnt(8)" ::: "memory");
    __builtin_amdgcn_s_barrier();

    // ---- half ks1 ----
#pragma unroll
    for (int m = 0; m < 4; ++m) af[m] = *(const int32x4*)(lds + 32768 + s + aoff + m * 1024);
#pragma unroll
    for (int n = 0; n < 4; ++n) bf[n] = *(const int32x4*)(lds + 98304 + s + boff + n * 1024);
    if constexpr (STG) {
#pragma unroll
        for (int c = 0; c < 4; ++c) gll(aP[c] + ko + 64, lds + 32768 + d + f + c * 4096);
    }
#pragma unroll
    for (int m = 0; m < 4; ++m) af[4 + m] = *(const int32x4*)(lds + 32768 + s + aoff + 4096 + m * 1024);
#pragma unroll
    for (int n = 0; n < 4; ++n) bf[4 + n] = *(const int32x4*)(lds + 98304 + s + boff + 4096 + n * 1024);
    CLUSTER(0, 0)
    if constexpr (STG) {
#pragma unroll
        for (int c = 0; c < 4; ++c) gll(bP[c] + ko + 64, lds + 98304 + d + f + c * 4096);
    }
    CLUSTER(0, 4)
    CLUSTER(4, 0)
    CLUSTER(4, 4)
    if constexpr (!TAIL) {
        asm volatile("s_waitcnt vmcnt(8)" ::: "memory");
        __builtin_amdgcn_s_barrier();
    }
}

// ---------------- Kernel 4: int8 MFMA GEMM, 256x256 tile, 8x8 blocking ----------------
// 256 threads = 4 waves (2M x 2N); wave-tile 128x128; acc[8][8] = 256 VGPR; ~350 total
// -> 1 wave/SIMD (__launch_bounds__(256,1)). Granule-major half-tiles (0 bank conflicts),
// dbuf-2 slots, counted vmcnt(8), compiler-counted lgkm, 2 barriers per K-tile.
__global__ __launch_bounds__(256, 1) void gemm_kernel(const signed char* __restrict__ xq,
                                                      const signed char* __restrict__ wq,
                                                      const float* __restrict__ beta,
                                                      const float* __restrict__ alpha_p,
                                                      float* __restrict__ out) {
    extern __shared__ signed char lds[];   // 131072
    const int tid = threadIdx.x;
    const int lane = tid & 63;
    const int wave = tid >> 6;             // 0..3
    const int wm = wave >> 1;              // 0..1
    const int wn = wave & 1;               // 0..1
    const int row0 = blockIdx.x * 256;
    const int col0 = blockIdx.y * 256;

    // staging: 4 x 16B chunks per half-tile region per thread (granule-major:
    // addr = g*1024 + kg*256 + r*16; chunk c: g = (tid>>6)+4c, kg=(tid>>4)&3, r=tid&15)
    const int f = tid * 16;
    const int rowb = ((tid >> 6) << 4) + (tid & 15);
    const int skg = ((tid >> 4) & 3) << 4;
    const signed char* aP[4];
    const signed char* bP[4];
#pragma unroll
    for (int c = 0; c < 4; ++c) {
        aP[c] = xq + (size_t)(row0 + rowb + 64 * c) * IN_DIM + skg;
        bP[c] = wq + (size_t)(col0 + rowb + 64 * c) * IN_DIM + skg;
    }

    const int kr = (lane >> 4) * 256 + (lane & 15) * 16;
    const int aoff = wm * 8192 + kr;       // + mh*4096 + m*1024
    const int boff = wn * 8192 + kr;       // + nh*4096 + n*1024

    int32x4 acc[8][8] = {};

    // prologue: tile 0's four half-tile regions into slot 0 (consumption order)
#pragma unroll
    for (int c = 0; c < 4; ++c) gll(aP[c], lds + f + c * 4096);               // Ah0
#pragma unroll
    for (int c = 0; c < 4; ++c) gll(bP[c], lds + 65536 + f + c * 4096);       // Bh0
#pragma unroll
    for (int c = 0; c < 4; ++c) gll(aP[c] + 64, lds + 32768 + f + c * 4096);  // Ah1
#pragma unroll
    for (int c = 0; c < 4; ++c) gll(bP[c] + 64, lds + 98304 + f + c * 4096);  // Bh1
    asm volatile("s_waitcnt vmcnt(8)" ::: "memory");                          // Ah0,Bh0 landed
    __builtin_amdgcn_s_barrier();

    for (int T = 0; T < NKT - 1; ++T)
        ktile<true, false>(T, lds, acc, aoff, boff, f, aP, bP);
    ktile<false, true>(NKT - 1, lds, acc, aoff, boff, f, aP, bP);

    // epilogue: dequant + store (C layout: col=lane&15, row=(lane>>4)*4+reg)
    const float alpha = *alpha_p;
#pragma unroll
    for (int mi = 0; mi < 8; ++mi) {
        int rbase = row0 + wm * 128 + mi * 16 + ((lane >> 4) << 2);
#pragma unroll
        for (int r = 0; r < 4; ++r) {
            int row = rbase + r;
            float scale = alpha * beta[row];
#pragma unroll
            for (int n = 0; n < 8; ++n) {
                int col = col0 + wn * 128 + n * 16 + (lane & 15);
                out[(size_t)row * OUT_DIM + col] = (float)acc[mi][n][r] * scale;
            }
        }
    }
}

extern "C" void kernel_launch(void* const* d_in, const int* in_sizes, int n_in,
                              void* d_out, int out_size, void* d_ws, size_t ws_size,
                              hipStream_t stream) {
    const float* x = (const float*)d_in[0];
    const float* w = (const float*)d_in[1];
    float* out = (float*)d_out;

    const int tokens = in_sizes[0] / IN_DIM;          // 16384
    const int n_w = in_sizes[1];                      // 4194304
    const int n_w4 = n_w / 4;

    char* ws = (char*)d_ws;
    double* d_sum = (double*)ws;                      // 8 B
    float* d_alpha = (float*)(ws + 8);                // 4 B
    float* d_beta = (float*)(ws + 256);               // tokens * 4 B
    signed char* d_wq = (signed char*)(ws + 256 + 65536);
    signed char* d_xq = d_wq + (size_t)n_w;

    hipMemsetAsync(d_ws, 0, 16, stream);

    absum_kernel<<<1024, 256, 0, stream>>>(w, d_sum, n_w4);
    quantw_kernel<<<(n_w4 + 255) / 256, 256, 0, stream>>>(w, d_sum, d_wq, d_alpha, n_w4);
    quantx_kernel<<<(tokens + 3) / 4, 256, 0, stream>>>(x, d_xq, d_beta, tokens);

    hipFuncSetAttribute((const void*)gemm_kernel,
                        hipFuncAttributeMaxDynamicSharedMemorySize, 131072);

    dim3 grid(16384 / 256, OUT_DIM / 256);            // (64, 8)
    gemm_kernel<<<grid, 256, 131072, stream>>>(d_xq, d_wq, d_beta, d_alpha, out);
}